// Round 1
// baseline (1135.630 us; speedup 1.0000x reference)
//
#include <hip/hip_runtime.h>

namespace {

constexpr int Bn = 1024;  // batch
constexpr int Tn = 1024;  // timesteps
constexpr int Hn = 50;    // hidden
constexpr int Pn = 16;    // params per (b,t)

__device__ __forceinline__ float bcast_lane(float v, int k) {
    return __builtin_bit_cast(float, __builtin_amdgcn_readlane(__builtin_bit_cast(int, v), k));
}
__device__ __forceinline__ float fast_rcp(float x) { return __builtin_amdgcn_rcpf(x); }
__device__ __forceinline__ float fast_sigmoid(float x) {
    return fast_rcp(1.0f + __expf(-x));
}
__device__ __forceinline__ float fast_tanh(float x) {
    // tanh(x) = 1 - 2/(exp(2x)+1); saturates correctly at +/-1 for large |x|
    return 1.0f - 2.0f * fast_rcp(__expf(2.0f * x) + 1.0f);
}

// One block (64 threads = 1 wave) per batch element. Lane j < 50 owns hidden
// unit j and its 4 gate rows (i,f,g,o). W_hh rows held in VGPRs (200 floats).
// h broadcast via v_readlane (VALU pipe, no LDS traffic).
__global__ __launch_bounds__(64, 1)
void lstm_fused(const float* __restrict__ x, const float* __restrict__ params,
                const float* __restrict__ W_ih, const float* __restrict__ W_hh,
                const float* __restrict__ b_ih, const float* __restrict__ b_hh,
                const float* __restrict__ W_lin, const float* __restrict__ b_lin,
                float* __restrict__ out)
{
    const int b = blockIdx.x;
    const int j = threadIdx.x;            // lane id, 0..63
    const int jj = (j < Hn) ? j : Hn - 1; // clamped row index for safe loads
                                          // (lanes 50..63 compute garbage h that
                                          //  is never read: readlane only k<50,
                                          //  and their wl_h is 0)

    // --- load per-lane weights into registers (once) ---
    float w0[Hn], w1[Hn], w2[Hn], w3[Hn];
    #pragma unroll
    for (int k = 0; k < Hn; ++k) {
        w0[k] = W_hh[(0 * Hn + jj) * Hn + k];
        w1[k] = W_hh[(1 * Hn + jj) * Hn + k];
        w2[k] = W_hh[(2 * Hn + jj) * Hn + k];
        w3[k] = W_hh[(3 * Hn + jj) * Hn + k];
    }
    const float wih0 = W_ih[0 * Hn + jj];
    const float wih1 = W_ih[1 * Hn + jj];
    const float wih2 = W_ih[2 * Hn + jj];
    const float wih3 = W_ih[3 * Hn + jj];
    const float bb0 = b_ih[0 * Hn + jj] + b_hh[0 * Hn + jj];
    const float bb1 = b_ih[1 * Hn + jj] + b_hh[1 * Hn + jj];
    const float bb2 = b_ih[2 * Hn + jj] + b_hh[2 * Hn + jj];
    const float bb3 = b_ih[3 * Hn + jj] + b_hh[3 * Hn + jj];

    // output projection weights: lanes 0..49 carry h part; lanes 48..63 carry
    // params part p = j&15 (48 ≡ 0 mod 16 so j&15 is exactly p).
    const float wl_h = (j < Hn) ? W_lin[j] : 0.0f;
    const float wl_p = (j >= 48) ? W_lin[Hn + (j & 15)] : 0.0f;
    const float blin = b_lin[0];

    const float* xb = x + (size_t)b * Tn;
    const float* pb = params + ((size_t)b * Tn) * Pn + (j & 15);
    float* ob = out + (size_t)b * Tn;

    float h = 0.0f, c = 0.0f;
    float xt = xb[0];
    float pv = pb[0];

    for (int t = 0; t < Tn; ++t) {
        // prefetch next step's inputs (latency hides under the matvec)
        float xt_n = 0.0f, pv_n = 0.0f;
        if (t + 1 < Tn) {
            xt_n = xb[t + 1];
            pv_n = pb[(size_t)(t + 1) * Pn];
        }

        // gates = x_t * W_ih + (b_ih + b_hh) + h_prev @ W_hh^T
        float a0 = fmaf(xt, wih0, bb0);
        float a1 = fmaf(xt, wih1, bb1);
        float a2 = fmaf(xt, wih2, bb2);
        float a3 = fmaf(xt, wih3, bb3);
        #pragma unroll
        for (int k = 0; k < Hn; ++k) {
            const float hk = bcast_lane(h, k);   // v_readlane, lane k const
            a0 = fmaf(hk, w0[k], a0);
            a1 = fmaf(hk, w1[k], a1);
            a2 = fmaf(hk, w2[k], a2);
            a3 = fmaf(hk, w3[k], a3);
        }

        const float ig = fast_sigmoid(a0);
        const float fg = fast_sigmoid(a1);
        const float gg = fast_tanh(a2);
        const float og = fast_sigmoid(a3);
        c = fmaf(fg, c, ig * gg);
        h = og * fast_tanh(c);

        // fused output projection: out = sum_j h_j*Wl[j] + sum_p prm_p*Wl[50+p] + b
        float val = fmaf(h, wl_h, pv * wl_p);
        #pragma unroll
        for (int m = 32; m >= 1; m >>= 1) val += __shfl_xor(val, m, 64);
        if (j == 0) ob[t] = val + blin;

        xt = xt_n;
        pv = pv_n;
    }
}

} // namespace

extern "C" void kernel_launch(void* const* d_in, const int* in_sizes, int n_in,
                              void* d_out, int out_size, void* d_ws, size_t ws_size,
                              hipStream_t stream) {
    const float* x      = (const float*)d_in[0];
    const float* params = (const float*)d_in[1];
    const float* W_ih   = (const float*)d_in[2];
    const float* W_hh   = (const float*)d_in[3];
    const float* b_ih   = (const float*)d_in[4];
    const float* b_hh   = (const float*)d_in[5];
    const float* W_lin  = (const float*)d_in[6];
    const float* b_lin  = (const float*)d_in[7];
    float* out = (float*)d_out;

    lstm_fused<<<dim3(Bn), dim3(64), 0, stream>>>(
        x, params, W_ih, W_hh, b_ih, b_hh, W_lin, b_lin, out);
}

// Round 2
// 1096.995 us; speedup vs baseline: 1.0352x; 1.0352x over previous
//
#include <hip/hip_runtime.h>

namespace {

constexpr int Bn = 1024;  // batch
constexpr int Tn = 1024;  // timesteps
constexpr int Hn = 50;    // hidden
constexpr int Pn = 16;    // params per (b,t)
constexpr int KH = 25;    // k-half per wave

__device__ __forceinline__ float bcast_lane(float v, int k) {
    return __builtin_bit_cast(float, __builtin_amdgcn_readlane(__builtin_bit_cast(int, v), k));
}
__device__ __forceinline__ float fast_rcp(float x) { return __builtin_amdgcn_rcpf(x); }
__device__ __forceinline__ float fast_sigmoid(float x) {
    return fast_rcp(1.0f + __expf(-x));
}
__device__ __forceinline__ float fast_tanh(float x) {
    return 1.0f - 2.0f * fast_rcp(__expf(2.0f * x) + 1.0f);
}

// 2 batch elements per 256-thread block; each batch owned by a PAIR of waves
// that split the k-dimension of the h @ W_hh^T matvec (k 0..24 / 25..49).
// Lane j < 50 owns hidden unit j (rows j, j+50, j+100, j+150). Weights (100
// floats/lane) are pinned into VGPRs with an empty volatile asm so the
// compiler cannot sink the loads back into the loop (round-1 failure mode:
// VGPR_Count=116 proved remat-from-global each step). Partial gate sums are
// exchanged via an LDS ping-pong with ONE __syncthreads per step; both waves
// redundantly compute the (identical) c/h update so h stays lane-local for
// the v_readlane broadcast. Grid 512 blocks -> 2 waves/SIMD latency hiding.
__global__ __launch_bounds__(256, 2)
void lstm_fused(const float* __restrict__ x, const float* __restrict__ params,
                const float* __restrict__ W_ih, const float* __restrict__ W_hh,
                const float* __restrict__ b_ih, const float* __restrict__ b_hh,
                const float* __restrict__ W_lin, const float* __restrict__ b_lin,
                float* __restrict__ out)
{
    __shared__ float4 part[2][4][64];  // [t parity][wave][lane] = 8 KB

    const int tid  = threadIdx.x;
    const int lane = tid & 63;
    const int wid  = __builtin_amdgcn_readfirstlane(tid >> 6);  // 0..3, SGPR
    const int half = wid & 1;            // 0: x-wave (k 0..24), 1: y-wave (k 25..49)
    const int k0   = half * KH;
    const int b    = blockIdx.x * 2 + (wid >> 1);
    const int jj   = (lane < Hn) ? lane : Hn - 1;  // clamp: lanes 50..63 mirror
                                                   // unit 49 (finite, never read)

    // --- per-lane W_hh rows (this wave's k-half) into registers, pinned ---
    float w0[KH], w1[KH], w2[KH], w3[KH];
    #pragma unroll
    for (int k = 0; k < KH; ++k) {
        w0[k] = W_hh[(0 * Hn + jj) * Hn + k0 + k];
        w1[k] = W_hh[(1 * Hn + jj) * Hn + k0 + k];
        w2[k] = W_hh[(2 * Hn + jj) * Hn + k0 + k];
        w3[k] = W_hh[(3 * Hn + jj) * Hn + k0 + k];
    }
    #pragma unroll
    for (int k = 0; k < KH; ++k) {
        asm volatile("" : "+v"(w0[k]), "+v"(w1[k]), "+v"(w2[k]), "+v"(w3[k]));
    }

    // x-gate weights + combined bias (folded by x-wave only)
    const float wih0 = W_ih[0 * Hn + jj];
    const float wih1 = W_ih[1 * Hn + jj];
    const float wih2 = W_ih[2 * Hn + jj];
    const float wih3 = W_ih[3 * Hn + jj];
    const float bb0 = b_ih[0 * Hn + jj] + b_hh[0 * Hn + jj];
    const float bb1 = b_ih[1 * Hn + jj] + b_hh[1 * Hn + jj];
    const float bb2 = b_ih[2 * Hn + jj] + b_hh[2 * Hn + jj];
    const float bb3 = b_ih[3 * Hn + jj] + b_hh[3 * Hn + jj];

    // projection weights (used by y-wave)
    const float wl_h = (lane < Hn) ? W_lin[lane] : 0.0f;
    const float wl_p = (lane >= 48) ? W_lin[Hn + (lane & 15)] : 0.0f;
    const float blin = b_lin[0];

    const float* xb = x + (size_t)b * Tn;
    const float* pb = params + ((size_t)b * Tn) * Pn + (lane & 15);
    float* ob = out + (size_t)b * Tn;

    float h = 0.0f, c = 0.0f;
    float xt = (half == 0) ? xb[0] : 0.0f;   // x-wave streams x
    float pv = (half == 1) ? pb[0] : 0.0f;   // y-wave streams params

    for (int t = 0; t < Tn; ++t) {
        // prefetch t+1 inputs early (latency hides under matvec + barrier)
        float xt_n = 0.0f, pv_n = 0.0f;
        if (t + 1 < Tn) {
            if (half == 0) xt_n = xb[t + 1];
            else           pv_n = pb[(size_t)(t + 1) * Pn];
        }

        // partial gates for this wave's k-half
        float a0, a1, a2, a3;
        if (half == 0) {
            a0 = fmaf(xt, wih0, bb0);
            a1 = fmaf(xt, wih1, bb1);
            a2 = fmaf(xt, wih2, bb2);
            a3 = fmaf(xt, wih3, bb3);
        } else {
            a0 = a1 = a2 = a3 = 0.0f;
        }
        #pragma unroll
        for (int k = 0; k < KH; ++k) {
            const float hk = bcast_lane(h, k0 + k);  // v_readlane (SGPR idx)
            a0 = fmaf(hk, w0[k], a0);
            a1 = fmaf(hk, w1[k], a1);
            a2 = fmaf(hk, w2[k], a2);
            a3 = fmaf(hk, w3[k], a3);
        }

        // exchange partials with partner wave (ping-pong, 1 barrier/step)
        part[t & 1][wid][lane] = make_float4(a0, a1, a2, a3);
        __syncthreads();
        const float4 p = part[t & 1][wid ^ 1][lane];
        a0 += p.x; a1 += p.y; a2 += p.z; a3 += p.w;

        // activations + state update (duplicated in both waves -> h lane-local)
        const float ig = fast_sigmoid(a0);
        const float fg = fast_sigmoid(a1);
        const float gg = fast_tanh(a2);
        const float og = fast_sigmoid(a3);
        c = fmaf(fg, c, ig * gg);
        h = og * fast_tanh(c);

        // fused output projection on the y-wave (balances the x-fold work)
        if (half == 1) {
            float val = fmaf(h, wl_h, pv * wl_p);
            #pragma unroll
            for (int m = 32; m >= 1; m >>= 1) val += __shfl_xor(val, m, 64);
            if (lane == 0) ob[t] = val + blin;
        }

        xt = xt_n;
        pv = pv_n;
    }
}

} // namespace

extern "C" void kernel_launch(void* const* d_in, const int* in_sizes, int n_in,
                              void* d_out, int out_size, void* d_ws, size_t ws_size,
                              hipStream_t stream) {
    const float* x      = (const float*)d_in[0];
    const float* params = (const float*)d_in[1];
    const float* W_ih   = (const float*)d_in[2];
    const float* W_hh   = (const float*)d_in[3];
    const float* b_ih   = (const float*)d_in[4];
    const float* b_hh   = (const float*)d_in[5];
    const float* W_lin  = (const float*)d_in[6];
    const float* b_lin  = (const float*)d_in[7];
    float* out = (float*)d_out;

    lstm_fused<<<dim3(Bn / 2), dim3(256), 0, stream>>>(
        x, params, W_ih, W_hh, b_ih, b_hh, W_lin, b_lin, out);
}

// Round 3
// 588.702 us; speedup vs baseline: 1.9290x; 1.8634x over previous
//
#include <hip/hip_runtime.h>

namespace {

constexpr int Bn = 1024;  // batch
constexpr int Tn = 1024;  // timesteps
constexpr int Hn = 50;    // hidden
constexpr int Pn = 16;    // params per (b,t)
constexpr int KP = 25;    // h pairs (H=50 -> 25 half2)

typedef _Float16 h2 __attribute__((ext_vector_type(2)));

__device__ __forceinline__ float fast_rcp(float x) { return __builtin_amdgcn_rcpf(x); }
__device__ __forceinline__ float fast_sigmoid(float x) {
    return fast_rcp(1.0f + __expf(-x));
}
__device__ __forceinline__ float fast_tanh(float x) {
    return 1.0f - 2.0f * fast_rcp(__expf(2.0f * x) + 1.0f);
}
__device__ __forceinline__ float fdot2(h2 a, h2 b, float c) {
    return __builtin_amdgcn_fdot2(a, b, c, false);  // v_dot2_f32_f16, fp32 acc
}

// ---------------------------------------------------------------------------
// Pre-kernel: pp[b,t] = params[b,t,:] . W_lin[50:66]  (no recurrence; ~12us,
// memory-bound). Removes the 64MB params tensor from the LSTM kernel.
// ---------------------------------------------------------------------------
__global__ __launch_bounds__(256)
void params_proj(const float* __restrict__ params, const float* __restrict__ W_lin,
                 float* __restrict__ pp)
{
    const int i = blockIdx.x * 256 + threadIdx.x;      // 0 .. B*T-1 (exact grid)
    const float4* p4 = (const float4*)(params + (size_t)i * Pn);
    const float4 a = p4[0], b = p4[1], c = p4[2], d = p4[3];
    const float* wl = W_lin + Hn;
    float s;
    s  = a.x * wl[ 0] + a.y * wl[ 1] + a.z * wl[ 2] + a.w * wl[ 3];
    s += b.x * wl[ 4] + b.y * wl[ 5] + b.z * wl[ 6] + b.w * wl[ 7];
    s += c.x * wl[ 8] + c.y * wl[ 9] + c.z * wl[10] + c.w * wl[11];
    s += d.x * wl[12] + d.y * wl[13] + d.z * wl[14] + d.w * wl[15];
    pp[i] = s;
}

// ---------------------------------------------------------------------------
// Core: 1 wave per batch element (1024 blocks x 64 thr = 1 wave/SIMD chip-wide).
// Lane j owns hidden unit j (gate rows j, j+50, j+100, j+150). Weights live in
// VGPRs as 125 packed half2 (4 gates + out-proj). waves_per_eu(1,1) removes the
// compiler's occupancy incentive to spill/remat (rounds 1-2 failure: scratch
// reloads of weights every step = VMEM-gather bound at ~2540cy/step).
// h broadcast: pack (h_j, h_j^1) via DPP quad-perm + cvt_pkrtz, then 25
// v_readlane -> SGPR pairs feed v_dot2_f32_f16 directly (1 SGPR/instr legal).
// Matvec: 100 dot2. Output projection reuses the same SGPR pairs: +25 dot2,
// no shuffle-reduce. fp32 activations/c/x-path.
// ---------------------------------------------------------------------------
__global__ __attribute__((amdgpu_flat_work_group_size(64, 64), amdgpu_waves_per_eu(1, 1)))
void lstm_core(const float* __restrict__ x, const float* __restrict__ W_ih,
               const float* __restrict__ W_hh, const float* __restrict__ b_ih,
               const float* __restrict__ b_hh, const float* __restrict__ W_lin,
               const float* __restrict__ b_lin, const float* __restrict__ pp,
               float* __restrict__ out)
{
    const int b    = blockIdx.x;
    const int lane = threadIdx.x;                 // 0..63
    const int jj   = (lane < Hn) ? lane : Hn - 1; // lanes 50..63: harmless dup

    // --- pack W_hh rows (fp16 RNE) into 100 VGPRs + 25 for W_lin h-part ---
    h2 w0[KP], w1[KP], w2[KP], w3[KP], wl[KP];
    const float* r0 = W_hh + (size_t)(0 * Hn + jj) * Hn;
    const float* r1 = W_hh + (size_t)(1 * Hn + jj) * Hn;
    const float* r2 = W_hh + (size_t)(2 * Hn + jj) * Hn;
    const float* r3 = W_hh + (size_t)(3 * Hn + jj) * Hn;
    #pragma unroll
    for (int k = 0; k < KP; ++k) {
        w0[k] = h2{(_Float16)r0[2 * k], (_Float16)r0[2 * k + 1]};
        w1[k] = h2{(_Float16)r1[2 * k], (_Float16)r1[2 * k + 1]};
        w2[k] = h2{(_Float16)r2[2 * k], (_Float16)r2[2 * k + 1]};
        w3[k] = h2{(_Float16)r3[2 * k], (_Float16)r3[2 * k + 1]};
        wl[k] = h2{(_Float16)W_lin[2 * k], (_Float16)W_lin[2 * k + 1]};
    }
    #pragma unroll
    for (int k = 0; k < KP; ++k) {
        asm volatile("" : "+v"(w0[k]), "+v"(w1[k]), "+v"(w2[k]), "+v"(w3[k]), "+v"(wl[k]));
    }

    const float wih0 = W_ih[0 * Hn + jj];
    const float wih1 = W_ih[1 * Hn + jj];
    const float wih2 = W_ih[2 * Hn + jj];
    const float wih3 = W_ih[3 * Hn + jj];
    const float bb0 = b_ih[0 * Hn + jj] + b_hh[0 * Hn + jj];
    const float bb1 = b_ih[1 * Hn + jj] + b_hh[1 * Hn + jj];
    const float bb2 = b_ih[2 * Hn + jj] + b_hh[2 * Hn + jj];
    const float bb3 = b_ih[3 * Hn + jj] + b_hh[3 * Hn + jj];
    const float blin = b_lin[0];

    const float4* xb4 = (const float4*)(x + (size_t)b * Tn);
    const float4* pp4 = (const float4*)(pp + (size_t)b * Tn);
    float4* ob4 = (float4*)(out + (size_t)b * Tn);

    float h = 0.0f, c = 0.0f;
    int sp[KP];                      // SGPR-resident packed h pairs (uniform)
    #pragma unroll
    for (int k = 0; k < KP; ++k) sp[k] = 0;

    float4 xA = xb4[0], pA = pp4[0];

    for (int tt = 0; tt < Tn / 4; ++tt) {
        float4 xB = make_float4(0.f, 0.f, 0.f, 0.f), pB = xB;
        if (tt + 1 < Tn / 4) { xB = xb4[tt + 1]; pB = pp4[tt + 1]; }

        const float xs[4] = {xA.x, xA.y, xA.z, xA.w};
        const float ps[4] = {pA.x, pA.y, pA.z, pA.w};
        float o4[4];

        #pragma unroll
        for (int u = 0; u < 4; ++u) {
            // gates(t) from h(t-1): 100 x v_dot2_f32_f16, SGPR pair x VGPR pair
            float a0 = fmaf(xs[u], wih0, bb0);
            float a1 = fmaf(xs[u], wih1, bb1);
            float a2 = fmaf(xs[u], wih2, bb2);
            float a3 = fmaf(xs[u], wih3, bb3);
            #pragma unroll
            for (int k = 0; k < KP; ++k) {
                const h2 hp = __builtin_bit_cast(h2, sp[k]);
                a0 = fdot2(hp, w0[k], a0);
                a1 = fdot2(hp, w1[k], a1);
                a2 = fdot2(hp, w2[k], a2);
                a3 = fdot2(hp, w3[k], a3);
            }

            const float ig = fast_sigmoid(a0);
            const float fg = fast_sigmoid(a1);
            const float gg = fast_tanh(a2);
            const float og = fast_sigmoid(a3);
            c = fmaf(fg, c, ig * gg);
            h = og * fast_tanh(c);

            // pack (h_j, h_{j^1}): DPP quad-perm [1,0,3,2] is a free VALU op
            const int hi = __builtin_bit_cast(int, h);
            const int hj = __builtin_amdgcn_update_dpp(0, hi, 0xB1, 0xF, 0xF, true);
            const int packed = __builtin_bit_cast(int,
                __builtin_amdgcn_cvt_pkrtz(h, __builtin_bit_cast(float, hj)));

            // broadcast: even lanes hold (h_2k, h_2k+1); 25 readlanes -> SGPRs.
            // These serve BOTH this step's out-projection and next step's matvec.
            #pragma unroll
            for (int k = 0; k < KP; ++k)
                sp[k] = __builtin_amdgcn_readlane(packed, 2 * k);

            // out[t] = h . W_lin[0:50] + pp[t] + b  (uniform in every lane)
            float prj = ps[u] + blin;
            #pragma unroll
            for (int k = 0; k < KP; ++k)
                prj = fdot2(__builtin_bit_cast(h2, sp[k]), wl[k], prj);
            o4[u] = prj;
        }

        if (lane == 0) ob4[tt] = make_float4(o4[0], o4[1], o4[2], o4[3]);
        xA = xB; pA = pB;
    }
}

} // namespace

extern "C" void kernel_launch(void* const* d_in, const int* in_sizes, int n_in,
                              void* d_out, int out_size, void* d_ws, size_t ws_size,
                              hipStream_t stream) {
    const float* x      = (const float*)d_in[0];
    const float* params = (const float*)d_in[1];
    const float* W_ih   = (const float*)d_in[2];
    const float* W_hh   = (const float*)d_in[3];
    const float* b_ih   = (const float*)d_in[4];
    const float* b_hh   = (const float*)d_in[5];
    const float* W_lin  = (const float*)d_in[6];
    const float* b_lin  = (const float*)d_in[7];
    float* out = (float*)d_out;
    float* pp  = (float*)d_ws;  // B*T floats = 4 MB scratch

    params_proj<<<dim3(Bn * Tn / 256), dim3(256), 0, stream>>>(params, W_lin, pp);
    lstm_core<<<dim3(Bn), dim3(64), 0, stream>>>(
        x, W_ih, W_hh, b_ih, b_hh, W_lin, b_lin, pp, out);
}

// Round 5
// 488.309 us; speedup vs baseline: 2.3256x; 1.2056x over previous
//
#include <hip/hip_runtime.h>
#include <stdint.h>

namespace {

constexpr int Bn = 1024;  // batch
constexpr int Tn = 1024;  // timesteps
constexpr int Hn = 50;    // hidden
constexpr int Pn = 16;    // params per (b,t)
constexpr int KP = 25;    // h pairs (H=50 -> 25 half2)

typedef _Float16 h2 __attribute__((ext_vector_type(2)));

__device__ __forceinline__ float fast_rcp(float x) { return __builtin_amdgcn_rcpf(x); }
__device__ __forceinline__ float fast_sigmoid(float x) {
    return fast_rcp(1.0f + __expf(-x));
}
__device__ __forceinline__ float fast_tanh(float x) {
    return 1.0f - 2.0f * fast_rcp(__expf(2.0f * x) + 1.0f);
}
__device__ __forceinline__ float fdot2(h2 a, h2 b, float c) {
    return __builtin_amdgcn_fdot2(a, b, c, false);  // v_dot2_f32_f16, fp32 acc
}

// ---------------------------------------------------------------------------
// SPLIT PATH serial kernel: recurrence ONLY. 1 wave per batch element
// (1024 blocks = 1 wave/SIMD chip-wide). Lane j owns hidden unit j (gate rows
// j, j+50, j+100, j+150); W_hh lives in VGPRs as 100 packed half2. Projection
// is DEFERRED: per step we store the 25 packed (h_2k,h_2k+1) dwords to hbuf
// (layout [b][k][t] -> post-kernel reads coalesced; store ptr bumps 4B/step).
// Rationale (r3 post-mortem): fused projection cost ~51 instr + ~35 VGPRs of
// pressure; VGPR_Count=132 < live-set implied AGPR shuffling of weights.
// ---------------------------------------------------------------------------
__global__ __attribute__((amdgpu_flat_work_group_size(64, 64), amdgpu_waves_per_eu(1, 1)))
void lstm_core_h(const float* __restrict__ x, const float* __restrict__ W_ih,
                 const float* __restrict__ W_hh, const float* __restrict__ b_ih,
                 const float* __restrict__ b_hh, uint32_t* __restrict__ hbuf)
{
    const int b    = blockIdx.x;
    const int lane = threadIdx.x;                 // 0..63
    const int jj   = (lane < Hn) ? lane : Hn - 1; // lanes 50..63: harmless dup

    // --- pack W_hh rows (fp16 RNE) into 100 VGPRs, pinned ---
    h2 w0[KP], w1[KP], w2[KP], w3[KP];
    const float* r0 = W_hh + (size_t)(0 * Hn + jj) * Hn;
    const float* r1 = W_hh + (size_t)(1 * Hn + jj) * Hn;
    const float* r2 = W_hh + (size_t)(2 * Hn + jj) * Hn;
    const float* r3 = W_hh + (size_t)(3 * Hn + jj) * Hn;
    #pragma unroll
    for (int k = 0; k < KP; ++k) {
        w0[k] = h2{(_Float16)r0[2 * k], (_Float16)r0[2 * k + 1]};
        w1[k] = h2{(_Float16)r1[2 * k], (_Float16)r1[2 * k + 1]};
        w2[k] = h2{(_Float16)r2[2 * k], (_Float16)r2[2 * k + 1]};
        w3[k] = h2{(_Float16)r3[2 * k], (_Float16)r3[2 * k + 1]};
    }
    #pragma unroll
    for (int k = 0; k < KP; ++k) {
        asm volatile("" : "+v"(w0[k]), "+v"(w1[k]), "+v"(w2[k]), "+v"(w3[k]));
    }

    const float wih0 = W_ih[0 * Hn + jj];
    const float wih1 = W_ih[1 * Hn + jj];
    const float wih2 = W_ih[2 * Hn + jj];
    const float wih3 = W_ih[3 * Hn + jj];
    const float bb0 = b_ih[0 * Hn + jj] + b_hh[0 * Hn + jj];
    const float bb1 = b_ih[1 * Hn + jj] + b_hh[1 * Hn + jj];
    const float bb2 = b_ih[2 * Hn + jj] + b_hh[2 * Hn + jj];
    const float bb3 = b_ih[3 * Hn + jj] + b_hh[3 * Hn + jj];

    const float4* xb4 = (const float4*)(x + (size_t)b * Tn);

    // packed-h store: even lanes 0,2,..,48 own pair k=lane/2; [b][k][t] layout
    uint32_t* hb = hbuf + ((size_t)b * KP + (size_t)(lane >> 1)) * Tn;
    const bool writer = (lane < Hn) && ((lane & 1) == 0);

    float h = 0.0f, c = 0.0f;
    int sp[KP];
    #pragma unroll
    for (int k = 0; k < KP; ++k) sp[k] = 0;

    float4 xA = xb4[0];

    for (int tt = 0; tt < Tn / 4; ++tt) {
        float4 xB = make_float4(0.f, 0.f, 0.f, 0.f);
        if (tt + 1 < Tn / 4) xB = xb4[tt + 1];

        const float xs[4] = {xA.x, xA.y, xA.z, xA.w};

        #pragma unroll
        for (int u = 0; u < 4; ++u) {
            // gates(t) from h(t-1): 100 x v_dot2_f32_f16 (SGPR pair x VGPR pair)
            float a0 = fmaf(xs[u], wih0, bb0);
            float a1 = fmaf(xs[u], wih1, bb1);
            float a2 = fmaf(xs[u], wih2, bb2);
            float a3 = fmaf(xs[u], wih3, bb3);
            #pragma unroll
            for (int k = 0; k < KP; ++k) {
                const h2 hp = __builtin_bit_cast(h2, sp[k]);
                a0 = fdot2(hp, w0[k], a0);
                a1 = fdot2(hp, w1[k], a1);
                a2 = fdot2(hp, w2[k], a2);
                a3 = fdot2(hp, w3[k], a3);
            }

            const float ig = fast_sigmoid(a0);
            const float fg = fast_sigmoid(a1);
            const float gg = fast_tanh(a2);
            const float og = fast_sigmoid(a3);
            c = fmaf(fg, c, ig * gg);
            h = og * fast_tanh(c);

            // pack (h_j, h_{j^1}): DPP quad-perm [1,0,3,2] + cvt_pkrtz
            const int hi = __builtin_bit_cast(int, h);
            const int hj = __builtin_amdgcn_update_dpp(0, hi, 0xB1, 0xF, 0xF, true);
            const int packed = __builtin_bit_cast(int,
                __builtin_amdgcn_cvt_pkrtz(h, __builtin_bit_cast(float, hj)));

            // deferred projection: store packed h (fire-and-forget, 1 instr)
            if (writer) hb[tt * 4 + u] = (uint32_t)packed;

            // broadcast for next step's matvec: 25 readlanes -> SGPRs
            #pragma unroll
            for (int k = 0; k < KP; ++k)
                sp[k] = __builtin_amdgcn_readlane(packed, 2 * k);
        }
        xA = xB;
    }
}

// ---------------------------------------------------------------------------
// SPLIT PATH post-kernel: out[b,t] = h(b,t).Wlin[0:50] + params(b,t).Wlin[50:66]
// + b_lin. One thread per (b,t); hbuf [b][k][t] -> lane-coalesced dword loads.
// Memory-bound: ~168 MB traffic ~= 30 us.
// ---------------------------------------------------------------------------
__global__ __launch_bounds__(256)
void post_proj(const uint32_t* __restrict__ hbuf, const float* __restrict__ params,
               const float* __restrict__ W_lin, const float* __restrict__ b_lin,
               float* __restrict__ out)
{
    const int i = blockIdx.x * 256 + threadIdx.x;  // 0 .. B*T-1 (exact grid)
    const int b = i >> 10;                         // Tn = 1024
    const int t = i & (Tn - 1);

    float s = b_lin[0];
    const uint32_t* hp = hbuf + (size_t)b * KP * Tn + t;
    #pragma unroll
    for (int k = 0; k < KP; ++k) {
        const h2 wlk = h2{(_Float16)W_lin[2 * k], (_Float16)W_lin[2 * k + 1]};
        s = fdot2(__builtin_bit_cast(h2, hp[(size_t)k * Tn]), wlk, s);
    }

    const float4* p4 = (const float4*)(params + (size_t)i * Pn);
    const float4 a = p4[0], bq = p4[1], cq = p4[2], dq = p4[3];
    const float* wp = W_lin + Hn;
    s += a.x  * wp[ 0] + a.y  * wp[ 1] + a.z  * wp[ 2] + a.w  * wp[ 3];
    s += bq.x * wp[ 4] + bq.y * wp[ 5] + bq.z * wp[ 6] + bq.w * wp[ 7];
    s += cq.x * wp[ 8] + cq.y * wp[ 9] + cq.z * wp[10] + cq.w * wp[11];
    s += dq.x * wp[12] + dq.y * wp[13] + dq.z * wp[14] + dq.w * wp[15];
    out[i] = s;
}

// ---------------------------------------------------------------------------
// FALLBACK (ws too small for hbuf): round-3 fused kernels, unchanged.
// ---------------------------------------------------------------------------
__global__ __launch_bounds__(256)
void params_proj(const float* __restrict__ params, const float* __restrict__ W_lin,
                 float* __restrict__ pp)
{
    const int i = blockIdx.x * 256 + threadIdx.x;
    const float4* p4 = (const float4*)(params + (size_t)i * Pn);
    const float4 a = p4[0], b = p4[1], c = p4[2], d = p4[3];
    const float* wl = W_lin + Hn;
    float s;
    s  = a.x * wl[ 0] + a.y * wl[ 1] + a.z * wl[ 2] + a.w * wl[ 3];
    s += b.x * wl[ 4] + b.y * wl[ 5] + b.z * wl[ 6] + b.w * wl[ 7];
    s += c.x * wl[ 8] + c.y * wl[ 9] + c.z * wl[10] + c.w * wl[11];
    s += d.x * wl[12] + d.y * wl[13] + d.z * wl[14] + d.w * wl[15];
    pp[i] = s;
}

__global__ __attribute__((amdgpu_flat_work_group_size(64, 64), amdgpu_waves_per_eu(1, 1)))
void lstm_core_fused(const float* __restrict__ x, const float* __restrict__ W_ih,
                     const float* __restrict__ W_hh, const float* __restrict__ b_ih,
                     const float* __restrict__ b_hh, const float* __restrict__ W_lin,
                     const float* __restrict__ b_lin, const float* __restrict__ pp,
                     float* __restrict__ out)
{
    const int b    = blockIdx.x;
    const int lane = threadIdx.x;
    const int jj   = (lane < Hn) ? lane : Hn - 1;

    h2 w0[KP], w1[KP], w2[KP], w3[KP], wl[KP];
    const float* r0 = W_hh + (size_t)(0 * Hn + jj) * Hn;
    const float* r1 = W_hh + (size_t)(1 * Hn + jj) * Hn;
    const float* r2 = W_hh + (size_t)(2 * Hn + jj) * Hn;
    const float* r3 = W_hh + (size_t)(3 * Hn + jj) * Hn;
    #pragma unroll
    for (int k = 0; k < KP; ++k) {
        w0[k] = h2{(_Float16)r0[2 * k], (_Float16)r0[2 * k + 1]};
        w1[k] = h2{(_Float16)r1[2 * k], (_Float16)r1[2 * k + 1]};
        w2[k] = h2{(_Float16)r2[2 * k], (_Float16)r2[2 * k + 1]};
        w3[k] = h2{(_Float16)r3[2 * k], (_Float16)r3[2 * k + 1]};
        wl[k] = h2{(_Float16)W_lin[2 * k], (_Float16)W_lin[2 * k + 1]};
    }
    #pragma unroll
    for (int k = 0; k < KP; ++k) {
        asm volatile("" : "+v"(w0[k]), "+v"(w1[k]), "+v"(w2[k]), "+v"(w3[k]), "+v"(wl[k]));
    }

    const float wih0 = W_ih[0 * Hn + jj];
    const float wih1 = W_ih[1 * Hn + jj];
    const float wih2 = W_ih[2 * Hn + jj];
    const float wih3 = W_ih[3 * Hn + jj];
    const float bb0 = b_ih[0 * Hn + jj] + b_hh[0 * Hn + jj];
    const float bb1 = b_ih[1 * Hn + jj] + b_hh[1 * Hn + jj];
    const float bb2 = b_ih[2 * Hn + jj] + b_hh[2 * Hn + jj];
    const float bb3 = b_ih[3 * Hn + jj] + b_hh[3 * Hn + jj];
    const float blin = b_lin[0];

    const float4* xb4 = (const float4*)(x + (size_t)b * Tn);
    const float4* pp4 = (const float4*)(pp + (size_t)b * Tn);
    float4* ob4 = (float4*)(out + (size_t)b * Tn);

    float h = 0.0f, c = 0.0f;
    int sp[KP];
    #pragma unroll
    for (int k = 0; k < KP; ++k) sp[k] = 0;

    float4 xA = xb4[0], pA = pp4[0];

    for (int tt = 0; tt < Tn / 4; ++tt) {
        float4 xB = make_float4(0.f, 0.f, 0.f, 0.f), pB = xB;
        if (tt + 1 < Tn / 4) { xB = xb4[tt + 1]; pB = pp4[tt + 1]; }

        const float xs[4] = {xA.x, xA.y, xA.z, xA.w};
        const float ps[4] = {pA.x, pA.y, pA.z, pA.w};
        float o4[4];

        #pragma unroll
        for (int u = 0; u < 4; ++u) {
            float a0 = fmaf(xs[u], wih0, bb0);
            float a1 = fmaf(xs[u], wih1, bb1);
            float a2 = fmaf(xs[u], wih2, bb2);
            float a3 = fmaf(xs[u], wih3, bb3);
            #pragma unroll
            for (int k = 0; k < KP; ++k) {
                const h2 hp = __builtin_bit_cast(h2, sp[k]);
                a0 = fdot2(hp, w0[k], a0);
                a1 = fdot2(hp, w1[k], a1);
                a2 = fdot2(hp, w2[k], a2);
                a3 = fdot2(hp, w3[k], a3);
            }

            const float ig = fast_sigmoid(a0);
            const float fg = fast_sigmoid(a1);
            const float gg = fast_tanh(a2);
            const float og = fast_sigmoid(a3);
            c = fmaf(fg, c, ig * gg);
            h = og * fast_tanh(c);

            const int hi = __builtin_bit_cast(int, h);
            const int hj = __builtin_amdgcn_update_dpp(0, hi, 0xB1, 0xF, 0xF, true);
            const int packed = __builtin_bit_cast(int,
                __builtin_amdgcn_cvt_pkrtz(h, __builtin_bit_cast(float, hj)));

            #pragma unroll
            for (int k = 0; k < KP; ++k)
                sp[k] = __builtin_amdgcn_readlane(packed, 2 * k);

            float prj = ps[u] + blin;
            #pragma unroll
            for (int k = 0; k < KP; ++k)
                prj = fdot2(__builtin_bit_cast(h2, sp[k]), wl[k], prj);
            o4[u] = prj;
        }

        if (lane == 0) ob4[tt] = make_float4(o4[0], o4[1], o4[2], o4[3]);
        xA = xB; pA = pB;
    }
}

} // namespace

extern "C" void kernel_launch(void* const* d_in, const int* in_sizes, int n_in,
                              void* d_out, int out_size, void* d_ws, size_t ws_size,
                              hipStream_t stream) {
    const float* x      = (const float*)d_in[0];
    const float* params = (const float*)d_in[1];
    const float* W_ih   = (const float*)d_in[2];
    const float* W_hh   = (const float*)d_in[3];
    const float* b_ih   = (const float*)d_in[4];
    const float* b_hh   = (const float*)d_in[5];
    const float* W_lin  = (const float*)d_in[6];
    const float* b_lin  = (const float*)d_in[7];
    float* out = (float*)d_out;

    const size_t hbuf_bytes = (size_t)Bn * KP * Tn * sizeof(uint32_t);  // 100 MB

    if (ws_size >= hbuf_bytes) {
        uint32_t* hbuf = (uint32_t*)d_ws;
        lstm_core_h<<<dim3(Bn), dim3(64), 0, stream>>>(
            x, W_ih, W_hh, b_ih, b_hh, hbuf);
        post_proj<<<dim3(Bn * Tn / 256), dim3(256), 0, stream>>>(
            hbuf, params, W_lin, b_lin, out);
    } else {
        float* pp = (float*)d_ws;  // 4 MB
        params_proj<<<dim3(Bn * Tn / 256), dim3(256), 0, stream>>>(params, W_lin, pp);
        lstm_core_fused<<<dim3(Bn), dim3(64), 0, stream>>>(
            x, W_ih, W_hh, b_ih, b_hh, W_lin, b_lin, pp, out);
    }
}